// Round 1
// baseline (551.392 us; speedup 1.0000x reference)
//
#include <hip/hip_runtime.h>
#include <math.h>

#define Bn 2
#define Hn 12
#define Tn 512
#define Cn 768
#define HS 64
#define BH 24
#define MTOP 8
#define NCOMB 36
#define NEGV -1e30f

// combo tables: slots (0..7) for size-1 (8 combos) then size-2 (28 combos), lexicographic
__device__ __constant__ int C_SL0[NCOMB] = {
  0,1,2,3,4,5,6,7,
  0,0,0,0,0,0,0,
  1,1,1,1,1,1,
  2,2,2,2,2,
  3,3,3,3,
  4,4,4,
  5,5,
  6};
__device__ __constant__ int C_SL1[NCOMB] = {
  -1,-1,-1,-1,-1,-1,-1,-1,
  1,2,3,4,5,6,7,
  2,3,4,5,6,7,
  3,4,5,6,7,
  4,5,6,7,
  5,6,7,
  6,7,
  7};

// ---------------- GEMM 1: qkv = x @ W_attn^T + b_attn, scattered to per-head q/k/v ----
// C[m][n] = sum_k x[m][k]*W[n][k] + bias[n];  M=1024, N=2304, K=768
__global__ __launch_bounds__(256) void gemm_qkv(const float* __restrict__ x,
                                                const float* __restrict__ W,
                                                const float* __restrict__ bias,
                                                float* __restrict__ qh,
                                                float* __restrict__ kh,
                                                float* __restrict__ vh) {
    __shared__ float As[16][65];  // As[kk][m]
    __shared__ float Bs[16][65];  // Bs[kk][n]
    const int tile_n = blockIdx.x * 64;
    const int tile_m = blockIdx.y * 64;
    const int tid = threadIdx.x;
    const int tx = tid & 15, ty = tid >> 4;
    float acc[4][4] = {};
    for (int k0 = 0; k0 < Cn; k0 += 16) {
        for (int e = tid; e < 1024; e += 256) {
            int m = e >> 4, kk = e & 15;
            As[kk][m] = x[(tile_m + m) * Cn + k0 + kk];
        }
        for (int e = tid; e < 1024; e += 256) {
            int n = e >> 4, kk = e & 15;
            Bs[kk][n] = W[(tile_n + n) * Cn + k0 + kk];
        }
        __syncthreads();
        for (int kk = 0; kk < 16; ++kk) {
            float a[4], b[4];
            #pragma unroll
            for (int u = 0; u < 4; ++u) a[u] = As[kk][ty * 4 + u];
            #pragma unroll
            for (int u = 0; u < 4; ++u) b[u] = Bs[kk][tx * 4 + u];
            #pragma unroll
            for (int um = 0; um < 4; ++um)
                #pragma unroll
                for (int un = 0; un < 4; ++un)
                    acc[um][un] += a[um] * b[un];
        }
        __syncthreads();
    }
    for (int um = 0; um < 4; ++um) {
        int m = tile_m + ty * 4 + um;
        int bb = m >> 9, t = m & 511;
        for (int un = 0; un < 4; ++un) {
            int n = tile_n + tx * 4 + un;
            float val = acc[um][un] + bias[n];
            int part = n / Cn;        // 0=q, 1=k, 2=v
            int c = n - part * Cn;
            int h = c >> 6, d = c & 63;
            float* dst = (part == 0) ? qh : ((part == 1) ? kh : vh);
            dst[(((bb * Hn) + h) * Tn + t) * HS + d] = val;
        }
    }
}

// ---------------- DPP selection kernel: one block per (head, token i) -----------------
__global__ __launch_bounds__(256) void dpp_kernel(const float* __restrict__ qh,
                                                  const float* __restrict__ kh,
                                                  const float* __restrict__ vh,
                                                  float* __restrict__ yflat) {
    const int bh = blockIdx.x;   // 0..23
    const int i  = blockIdx.y;   // 0..511
    const int tid = threadIdx.x;

    const float* q     = qh + (bh * Tn + i) * HS;
    const float* kbase = kh + bh * Tn * HS;
    const float* vbase = vh + bh * Tn * HS;

    __shared__ float qi[HS];
    __shared__ float sim[Tn];
    __shared__ float rval[256];
    __shared__ int   ridx[256];
    __shared__ int   top_idx[MTOP];
    __shared__ int   tok[9];
    __shared__ float Kloc[9][HS + 1];
    __shared__ float Vloc[9][HS + 1];
    __shared__ float G[9][9];
    __shared__ float qd[9];
    __shared__ float score[NCOMB];
    __shared__ float wloc[NCOMB][3];
    __shared__ float probs[NCOMB];
    __shared__ int   hasValid;

    if (tid < HS) qi[tid] = q[tid];
    __syncthreads();

    // sim[j] = k_j . q_i for j<=i else -inf
    for (int j = tid; j < Tn; j += 256) {
        float s;
        if (j <= i) {
            const float4* kr = (const float4*)(kbase + j * HS);
            float acc = 0.f;
            #pragma unroll
            for (int d4 = 0; d4 < HS / 4; ++d4) {
                float4 kv = kr[d4];
                acc += kv.x * qi[d4 * 4 + 0];
                acc += kv.y * qi[d4 * 4 + 1];
                acc += kv.z * qi[d4 * 4 + 2];
                acc += kv.w * qi[d4 * 4 + 3];
            }
            s = acc;
        } else {
            s = -INFINITY;
        }
        sim[j] = s;
    }
    __syncthreads();

    // top-8 by 8 stable argmax passes (value desc, tie -> lower index == jax.lax.top_k)
    for (int p = 0; p < MTOP; ++p) {
        float bv = -INFINITY;
        int bi = 0x7fffffff;
        for (int j = tid; j < Tn; j += 256) {
            float v = sim[j];
            if (v > bv || (v == bv && j < bi)) { bv = v; bi = j; }
        }
        rval[tid] = bv; ridx[tid] = bi;
        __syncthreads();
        for (int off = 128; off > 0; off >>= 1) {
            if (tid < off) {
                float v2 = rval[tid + off]; int i2 = ridx[tid + off];
                if (v2 > rval[tid] || (v2 == rval[tid] && i2 < ridx[tid])) {
                    rval[tid] = v2; ridx[tid] = i2;
                }
            }
            __syncthreads();
        }
        if (tid == 0) {
            top_idx[p] = ridx[0];
            sim[ridx[0]] = -INFINITY;
        }
        __syncthreads();
    }

    // stage K/V rows for tokens {i} U top_idx
    if (tid < 9) tok[tid] = (tid == 0) ? i : top_idx[tid - 1];
    __syncthreads();
    for (int e = tid; e < 9 * HS; e += 256) {
        int a = e >> 6, d = e & 63;
        int t = tok[a];
        Kloc[a][d] = kbase[t * HS + d];
        Vloc[a][d] = vbase[t * HS + d];
    }
    __syncthreads();

    // gram G[a][b] = K_a . K_b ; qd[a] = K_a . q_i
    if (tid < 81) {
        int a = tid / 9, b = tid % 9;
        float acc = 0.f;
        for (int d = 0; d < HS; ++d) acc += Kloc[a][d] * Kloc[b][d];
        G[a][b] = acc;
    } else if (tid < 90) {
        int a = tid - 81;
        float acc = 0.f;
        for (int d = 0; d < HS; ++d) acc += Kloc[a][d] * qi[d];
        qd[a] = acc;
    }
    __syncthreads();

    const int n_cand = (i + 1 < MTOP) ? (i + 1) : MTOP;

    if (tid < NCOMB) {
        const int c = tid;
        const int sl0 = C_SL0[c], sl1 = C_SL1[c];
        const int sdim = (sl1 < 0) ? 1 : 2;
        const int a = sl0 + 1;
        const int b = (sl1 < 0) ? 0 : sl1 + 1;

        bool valid = (sl0 < n_cand) && (top_idx[sl0] != i);
        if (sdim == 2) valid = valid && (sl1 < n_cand) && (top_idx[sl1] != i);

        float det;
        if (sdim == 1) {
            det = G[0][0] * G[a][a] - G[0][a] * G[0][a];
        } else {
            float m00 = G[0][0], m01 = G[0][a], m02 = G[0][b];
            float m11 = G[a][a], m12 = G[a][b], m22 = G[b][b];
            det = m00 * (m11 * m22 - m12 * m12)
                - m01 * (m01 * m22 - m12 * m02)
                + m02 * (m01 * m12 - m11 * m02);
        }
        float sc = valid ? (logf(det + 1e-6f) / (float)(sdim + 1)) : NEGV;
        score[c] = sc;

        // per-combo attention softmax over s+1 tokens
        float d0 = qd[0] * 0.125f;
        float d1 = qd[a] * 0.125f;
        float d2 = (sdim == 2) ? qd[b] * 0.125f : -INFINITY;
        float mx = fmaxf(fmaxf(d0, d1), d2);
        float e0 = expf(d0 - mx), e1 = expf(d1 - mx);
        float e2 = (sdim == 2) ? expf(d2 - mx) : 0.f;
        float inv = 1.f / (e0 + e1 + e2);
        wloc[c][0] = e0 * inv;
        wloc[c][1] = e1 * inv;
        wloc[c][2] = e2 * inv;
    }
    __syncthreads();

    if (tid == 0) {
        float mx = -INFINITY;
        for (int c = 0; c < NCOMB; ++c) mx = fmaxf(mx, score[c]);
        float sum = 0.f;
        for (int c = 0; c < NCOMB; ++c) { float e = expf(score[c] - mx); probs[c] = e; sum += e; }
        float inv = 1.f / sum;
        for (int c = 0; c < NCOMB; ++c) probs[c] *= inv;
        hasValid = (mx > -1e29f) ? 1 : 0;
    }
    __syncthreads();

    if (tid < HS) {
        const int d = tid;
        float y;
        if (!hasValid) {
            y = Vloc[0][d];  // v[i]
        } else {
            float acc = 0.f;
            for (int c = 0; c < NCOMB; ++c) {
                const int a = C_SL0[c] + 1;
                const int sl1 = C_SL1[c];
                float o = wloc[c][0] * Vloc[0][d] + wloc[c][1] * Vloc[a][d];
                if (sl1 >= 0) o += wloc[c][2] * Vloc[sl1 + 1][d];
                acc += probs[c] * o;
            }
            y = acc;
        }
        const int bb = bh / Hn, h = bh % Hn;
        yflat[((bb * Tn) + i) * Cn + h * HS + d] = y;
    }
}

// ---------------- GEMM 2: out = y @ W_proj^T + b_proj ; M=1024, N=768, K=768 ----------
__global__ __launch_bounds__(256) void gemm_proj(const float* __restrict__ y,
                                                 const float* __restrict__ W,
                                                 const float* __restrict__ bias,
                                                 float* __restrict__ out) {
    __shared__ float As[16][65];
    __shared__ float Bs[16][65];
    const int tile_n = blockIdx.x * 64;
    const int tile_m = blockIdx.y * 64;
    const int tid = threadIdx.x;
    const int tx = tid & 15, ty = tid >> 4;
    float acc[4][4] = {};
    for (int k0 = 0; k0 < Cn; k0 += 16) {
        for (int e = tid; e < 1024; e += 256) {
            int m = e >> 4, kk = e & 15;
            As[kk][m] = y[(tile_m + m) * Cn + k0 + kk];
        }
        for (int e = tid; e < 1024; e += 256) {
            int n = e >> 4, kk = e & 15;
            Bs[kk][n] = W[(tile_n + n) * Cn + k0 + kk];
        }
        __syncthreads();
        for (int kk = 0; kk < 16; ++kk) {
            float a[4], b[4];
            #pragma unroll
            for (int u = 0; u < 4; ++u) a[u] = As[kk][ty * 4 + u];
            #pragma unroll
            for (int u = 0; u < 4; ++u) b[u] = Bs[kk][tx * 4 + u];
            #pragma unroll
            for (int um = 0; um < 4; ++um)
                #pragma unroll
                for (int un = 0; un < 4; ++un)
                    acc[um][un] += a[um] * b[un];
        }
        __syncthreads();
    }
    for (int um = 0; um < 4; ++um) {
        int m = tile_m + ty * 4 + um;
        for (int un = 0; un < 4; ++un) {
            int n = tile_n + tx * 4 + un;
            out[m * Cn + n] = acc[um][un] + bias[n];
        }
    }
}

extern "C" void kernel_launch(void* const* d_in, const int* in_sizes, int n_in,
                              void* d_out, int out_size, void* d_ws, size_t ws_size,
                              hipStream_t stream) {
    const float* x      = (const float*)d_in[0];
    const float* W_attn = (const float*)d_in[1];
    const float* b_attn = (const float*)d_in[2];
    const float* W_proj = (const float*)d_in[3];
    const float* b_proj = (const float*)d_in[4];
    float* out = (float*)d_out;

    float* ws = (float*)d_ws;
    const size_t per = (size_t)BH * Tn * HS;  // 786432 floats
    float* qh = ws;
    float* kh = ws + per;
    float* vh = ws + 2 * per;
    float* yf = ws + 3 * per;

    // qkv projection: grid = (N/64, M/64) = (36, 16)
    gemm_qkv<<<dim3(36, 16), 256, 0, stream>>>(x, W_attn, b_attn, qh, kh, vh);

    // dpp per (head, token)
    dpp_kernel<<<dim3(BH, Tn), 256, 0, stream>>>(qh, kh, vh, yf);

    // output projection: grid = (12, 16)
    gemm_proj<<<dim3(12, 16), 256, 0, stream>>>(yf, W_proj, b_proj, out);
}

// Round 2
// 348.166 us; speedup vs baseline: 1.5837x; 1.5837x over previous
//
#include <hip/hip_runtime.h>
#include <math.h>

#define Bn 2
#define Hn 12
#define Tn 512
#define Cn 768
#define HS 64
#define BH 24
#define MTOP 8
#define NCOMB 36
#define NEGV -1e30f

// combo tables: slots (0..7) for size-1 (8 combos) then size-2 (28 combos), lexicographic
__device__ __constant__ int C_SL0[NCOMB] = {
  0,1,2,3,4,5,6,7,
  0,0,0,0,0,0,0,
  1,1,1,1,1,1,
  2,2,2,2,2,
  3,3,3,3,
  4,4,4,
  5,5,
  6};
__device__ __constant__ int C_SL1[NCOMB] = {
  -1,-1,-1,-1,-1,-1,-1,-1,
  1,2,3,4,5,6,7,
  2,3,4,5,6,7,
  3,4,5,6,7,
  4,5,6,7,
  5,6,7,
  6,7,
  7};

// gram pair tables: 45 pairs (a<=b) over 9 tokens
__device__ __constant__ int PA[45] = {
  0,0,0,0,0,0,0,0,0,
  1,1,1,1,1,1,1,1,
  2,2,2,2,2,2,2,
  3,3,3,3,3,3,
  4,4,4,4,4,
  5,5,5,5,
  6,6,6,
  7,7,
  8};
__device__ __constant__ int PB[45] = {
  0,1,2,3,4,5,6,7,8,
  1,2,3,4,5,6,7,8,
  2,3,4,5,6,7,8,
  3,4,5,6,7,8,
  4,5,6,7,8,
  5,6,7,8,
  6,7,8,
  7,8,
  8};

// ---------------- GEMM 1: qkv = x @ W_attn^T + b_attn, scattered to per-head q/k/v ----
// M=1024 (rows of x), N=2304, K=768.  Tile 64(M) x 128(N), 256 thr, micro 4x8.
__global__ __launch_bounds__(256) void gemm_qkv(const float* __restrict__ x,
                                                const float* __restrict__ W,
                                                const float* __restrict__ bias,
                                                float* __restrict__ qh,
                                                float* __restrict__ kh,
                                                float* __restrict__ vh) {
    __shared__ float As[16][68];   // As[kk][m], m in [0,64)
    __shared__ float Bs[16][132];  // Bs[kk][n], n in [0,128)
    const int tn = blockIdx.x * 128;
    const int tm = blockIdx.y * 64;
    const int tid = threadIdx.x;
    const int tx = tid & 15;   // n dir, 8 each
    const int ty = tid >> 4;   // m dir, 4 each
    float acc[4][8] = {};
    for (int k0 = 0; k0 < Cn; k0 += 16) {
        {   // A tile: 64x16 = 1024 floats, 1 float4/thread
            int m = tid >> 2, kc = tid & 3;
            float4 va = *(const float4*)(x + (size_t)(tm + m) * Cn + k0 + kc * 4);
            As[kc*4+0][m] = va.x; As[kc*4+1][m] = va.y;
            As[kc*4+2][m] = va.z; As[kc*4+3][m] = va.w;
        }
        #pragma unroll
        for (int j = 0; j < 2; ++j) {   // B tile: 128x16 = 2048 floats
            int s = tid + 256 * j;
            int n = s >> 2, kc = s & 3;
            float4 vb = *(const float4*)(W + (size_t)(tn + n) * Cn + k0 + kc * 4);
            Bs[kc*4+0][n] = vb.x; Bs[kc*4+1][n] = vb.y;
            Bs[kc*4+2][n] = vb.z; Bs[kc*4+3][n] = vb.w;
        }
        __syncthreads();
        #pragma unroll
        for (int kk = 0; kk < 16; ++kk) {
            float4 a4 = *(const float4*)&As[kk][ty * 4];
            float4 b0 = *(const float4*)&Bs[kk][tx * 8];
            float4 b1 = *(const float4*)&Bs[kk][tx * 8 + 4];
            float am[4] = {a4.x, a4.y, a4.z, a4.w};
            float bn[8] = {b0.x, b0.y, b0.z, b0.w, b1.x, b1.y, b1.z, b1.w};
            #pragma unroll
            for (int um = 0; um < 4; ++um)
                #pragma unroll
                for (int un = 0; un < 8; ++un)
                    acc[um][un] += am[um] * bn[un];
        }
        __syncthreads();
    }
    // epilogue: scatter to per-head layout. tile's 128 cols lie in one qkv part.
    const int part = tn / Cn;                    // 0=q,1=k,2=v
    float* dst = (part == 0) ? qh : ((part == 1) ? kh : vh);
    const int c0 = tn - part * Cn + tx * 8;      // col within part
    const int h = c0 >> 6, d = c0 & 63;          // 8-chunk never crosses head boundary
    float bv[8];
    #pragma unroll
    for (int un = 0; un < 8; ++un) bv[un] = bias[tn + tx * 8 + un];
    #pragma unroll
    for (int um = 0; um < 4; ++um) {
        int m = tm + ty * 4 + um;
        int bb = m >> 9, t = m & 511;
        float* row = dst + ((size_t)((bb * Hn) + h) * Tn + t) * HS + d;
        float4 o0 = {acc[um][0] + bv[0], acc[um][1] + bv[1], acc[um][2] + bv[2], acc[um][3] + bv[3]};
        float4 o1 = {acc[um][4] + bv[4], acc[um][5] + bv[5], acc[um][6] + bv[6], acc[um][7] + bv[7]};
        *(float4*)(row)     = o0;
        *(float4*)(row + 4) = o1;
    }
}

// ---------------- DPP selection: one WAVE per (head, token) ---------------------------
// block = 256 thr = 4 waves; wave w handles token i = blockIdx.y*4 + w
__global__ __launch_bounds__(256) void dpp_kernel(const float* __restrict__ qh,
                                                  const float* __restrict__ kh,
                                                  const float* __restrict__ vh,
                                                  float* __restrict__ yflat) {
    const int bh = blockIdx.x;
    const int w = threadIdx.x >> 6;
    const int lane = threadIdx.x & 63;
    const int i = blockIdx.y * 4 + w;

    __shared__ float Ksh[4][9][68];
    __shared__ float Vsh[4][9][68];
    __shared__ float Gsh[4][81];
    __shared__ float qdsh[4][12];
    __shared__ float PW[4][36][4];

    const float* qp    = qh + (size_t)(bh * Tn + i) * HS;
    const float* kbase = kh + (size_t)bh * Tn * HS;
    const float* vbase = vh + (size_t)bh * Tn * HS;

    // q_i in registers (wave-uniform row)
    float4 qv[16];
    #pragma unroll
    for (int t = 0; t < 16; ++t) qv[t] = ((const float4*)qp)[t];

    // sim[j] for j = r*64 + lane, causal-masked
    const int rmax = i >> 6;
    float sv[8];
    #pragma unroll
    for (int r = 0; r < 8; ++r) {
        float s = -INFINITY;
        if (r <= rmax) {
            int j = r * 64 + lane;
            const float4* kr = (const float4*)(kbase + (size_t)j * HS);
            float acc = 0.f;
            #pragma unroll
            for (int t = 0; t < 16; ++t) {
                float4 kv = kr[t];
                acc += kv.x * qv[t].x; acc += kv.y * qv[t].y;
                acc += kv.z * qv[t].z; acc += kv.w * qv[t].w;
            }
            s = (j <= i) ? acc : -INFINITY;
        }
        sv[r] = s;
    }

    // qd0 = sim[i] (k_i . q_i) before any clearing
    float qd0 = 0.f;
    #pragma unroll
    for (int r = 0; r < 8; ++r) {
        float t = __shfl(sv[r], i & 63, 64);
        if (r == rmax) qd0 = t;
    }

    // top-8: 8 in-register butterfly argmax passes (value desc, tie -> lower index)
    float topv[8]; int topi[8];
    #pragma unroll
    for (int p = 0; p < MTOP; ++p) {
        float bv = -INFINITY; int bi = 0x7fffffff;
        #pragma unroll
        for (int r = 0; r < 8; ++r) {
            int j = r * 64 + lane;
            float v = sv[r];
            if (v > bv || (v == bv && j < bi)) { bv = v; bi = j; }
        }
        #pragma unroll
        for (int off = 32; off > 0; off >>= 1) {
            float ov = __shfl_xor(bv, off, 64);
            int   oi = __shfl_xor(bi, off, 64);
            if (ov > bv || (ov == bv && oi < bi)) { bv = ov; bi = oi; }
        }
        topv[p] = bv; topi[p] = bi;
        const int rs = bi >> 6, ls = bi & 63;
        #pragma unroll
        for (int r = 0; r < 8; ++r)
            if (r == rs && lane == ls) sv[r] = -INFINITY;
    }

    // validity bitmask per slot (uniform)
    const int n_cand = (i + 1 < MTOP) ? (i + 1) : MTOP;
    int vmask = 0;
    #pragma unroll
    for (int s = 0; s < MTOP; ++s)
        if (s < n_cand && topi[s] != i) vmask |= (1 << s);

    // stage K/V rows {i} U top_idx (coalesced: lane = d)
    #pragma unroll
    for (int a = 0; a < 9; ++a) {
        int t = (a == 0) ? i : topi[a - 1];
        Ksh[w][a][lane] = kbase[(size_t)t * HS + lane];
        Vsh[w][a][lane] = vbase[(size_t)t * HS + lane];
    }
    if (lane < 9) {
        float val = qd0;
        #pragma unroll
        for (int p = 0; p < 8; ++p) if (lane == p + 1) val = topv[p];
        qdsh[w][lane] = val;
    }
    __syncthreads();

    // gram: lane l < 45 computes pair (PA[l], PB[l])
    if (lane < 45) {
        const int a = PA[lane], b = PB[lane];
        const float4* ra = (const float4*)&Ksh[w][a][0];
        const float4* rb = (const float4*)&Ksh[w][b][0];
        float acc = 0.f;
        #pragma unroll
        for (int t = 0; t < 16; ++t) {
            float4 fa = ra[t], fb = rb[t];
            acc += fa.x * fb.x; acc += fa.y * fb.y;
            acc += fa.z * fb.z; acc += fa.w * fb.w;
        }
        Gsh[w][a * 9 + b] = acc;
        Gsh[w][b * 9 + a] = acc;
    }
    __syncthreads();

    // combos on lanes 0..35
    float score = -INFINITY;
    int ca = 0, cb = 0, sdim = 1;
    if (lane < NCOMB) {
        const int sl0 = C_SL0[lane], sl1 = C_SL1[lane];
        sdim = (sl1 < 0) ? 1 : 2;
        ca = sl0 + 1;
        cb = (sl1 < 0) ? 0 : sl1 + 1;
        bool valid = ((vmask >> sl0) & 1);
        if (sdim == 2) valid = valid && ((vmask >> sl1) & 1);
        float G00 = Gsh[w][0];
        float Gaa = Gsh[w][ca * 9 + ca];
        float G0a = Gsh[w][ca];
        float det;
        if (sdim == 1) {
            det = G00 * Gaa - G0a * G0a;
        } else {
            float G0b = Gsh[w][cb];
            float Gab = Gsh[w][ca * 9 + cb];
            float Gbb = Gsh[w][cb * 9 + cb];
            det = G00 * (Gaa * Gbb - Gab * Gab)
                - G0a * (G0a * Gbb - Gab * G0b)
                + G0b * (G0a * Gab - Gaa * G0b);
        }
        score = valid ? (logf(det + 1e-6f) / (float)(sdim + 1)) : NEGV;
    }
    // softmax over scores via butterfly (lanes>=36 contribute -inf / 0)
    float mx = score;
    #pragma unroll
    for (int off = 32; off > 0; off >>= 1) mx = fmaxf(mx, __shfl_xor(mx, off, 64));
    float e = (lane < NCOMB) ? expf(score - mx) : 0.f;
    float sum = e;
    #pragma unroll
    for (int off = 32; off > 0; off >>= 1) sum += __shfl_xor(sum, off, 64);
    const bool hasValid = (mx > -1e29f);

    if (lane < NCOMB) {
        float prob = e / sum;
        float d0 = qdsh[w][0]  * 0.125f;
        float d1 = qdsh[w][ca] * 0.125f;
        float d2 = (sdim == 2) ? qdsh[w][cb] * 0.125f : -INFINITY;
        float m2 = fmaxf(fmaxf(d0, d1), d2);
        float e0 = expf(d0 - m2), e1 = expf(d1 - m2);
        float e2 = (sdim == 2) ? expf(d2 - m2) : 0.f;
        float inv = prob / (e0 + e1 + e2);
        float4 pw = {e0 * inv, e1 * inv, e2 * inv, 0.f};
        *(float4*)&PW[w][lane][0] = pw;
    }
    __syncthreads();

    // y[d], d = lane
    const float v0 = Vsh[w][0][lane];
    float y;
    if (!hasValid) {
        y = v0;
    } else {
        float acc = 0.f;
        #pragma unroll
        for (int c = 0; c < NCOMB; ++c) {
            float4 pw = *(const float4*)&PW[w][c][0];
            int a = C_SL0[c] + 1;
            int b = (C_SL1[c] < 0) ? 0 : C_SL1[c] + 1;   // pw.z == 0 when sdim==1
            acc += pw.x * v0 + pw.y * Vsh[w][a][lane] + pw.z * Vsh[w][b][lane];
        }
        y = acc;
    }
    const int bb = bh / Hn, h = bh % Hn;
    yflat[((size_t)(bb * Tn + i)) * Cn + h * HS + lane] = y;
}

// ---------------- GEMM 2: out = y @ W_proj^T + b_proj ; M=1024, N=768, K=768 ----------
__global__ __launch_bounds__(256) void gemm_proj(const float* __restrict__ y,
                                                 const float* __restrict__ W,
                                                 const float* __restrict__ bias,
                                                 float* __restrict__ out) {
    __shared__ float As[16][68];
    __shared__ float Bs[16][132];
    const int tn = blockIdx.x * 128;
    const int tm = blockIdx.y * 64;
    const int tid = threadIdx.x;
    const int tx = tid & 15;
    const int ty = tid >> 4;
    float acc[4][8] = {};
    for (int k0 = 0; k0 < Cn; k0 += 16) {
        {
            int m = tid >> 2, kc = tid & 3;
            float4 va = *(const float4*)(y + (size_t)(tm + m) * Cn + k0 + kc * 4);
            As[kc*4+0][m] = va.x; As[kc*4+1][m] = va.y;
            As[kc*4+2][m] = va.z; As[kc*4+3][m] = va.w;
        }
        #pragma unroll
        for (int j = 0; j < 2; ++j) {
            int s = tid + 256 * j;
            int n = s >> 2, kc = s & 3;
            float4 vb = *(const float4*)(W + (size_t)(tn + n) * Cn + k0 + kc * 4);
            Bs[kc*4+0][n] = vb.x; Bs[kc*4+1][n] = vb.y;
            Bs[kc*4+2][n] = vb.z; Bs[kc*4+3][n] = vb.w;
        }
        __syncthreads();
        #pragma unroll
        for (int kk = 0; kk < 16; ++kk) {
            float4 a4 = *(const float4*)&As[kk][ty * 4];
            float4 b0 = *(const float4*)&Bs[kk][tx * 8];
            float4 b1 = *(const float4*)&Bs[kk][tx * 8 + 4];
            float am[4] = {a4.x, a4.y, a4.z, a4.w};
            float bn[8] = {b0.x, b0.y, b0.z, b0.w, b1.x, b1.y, b1.z, b1.w};
            #pragma unroll
            for (int um = 0; um < 4; ++um)
                #pragma unroll
                for (int un = 0; un < 8; ++un)
                    acc[um][un] += am[um] * bn[un];
        }
        __syncthreads();
    }
    float bv[8];
    #pragma unroll
    for (int un = 0; un < 8; ++un) bv[un] = bias[tn + tx * 8 + un];
    #pragma unroll
    for (int um = 0; um < 4; ++um) {
        int m = tm + ty * 4 + um;
        float* row = out + (size_t)m * Cn + tn + tx * 8;
        float4 o0 = {acc[um][0] + bv[0], acc[um][1] + bv[1], acc[um][2] + bv[2], acc[um][3] + bv[3]};
        float4 o1 = {acc[um][4] + bv[4], acc[um][5] + bv[5], acc[um][6] + bv[6], acc[um][7] + bv[7]};
        *(float4*)(row)     = o0;
        *(float4*)(row + 4) = o1;
    }
}

extern "C" void kernel_launch(void* const* d_in, const int* in_sizes, int n_in,
                              void* d_out, int out_size, void* d_ws, size_t ws_size,
                              hipStream_t stream) {
    const float* x      = (const float*)d_in[0];
    const float* W_attn = (const float*)d_in[1];
    const float* b_attn = (const float*)d_in[2];
    const float* W_proj = (const float*)d_in[3];
    const float* b_proj = (const float*)d_in[4];
    float* out = (float*)d_out;

    float* ws = (float*)d_ws;
    const size_t per = (size_t)BH * Tn * HS;  // 786432 floats
    float* qh = ws;
    float* kh = ws + per;
    float* vh = ws + 2 * per;
    float* yf = ws + 3 * per;

    // qkv projection: tiles 64x128 -> grid (2304/128, 1024/64) = (18, 16)
    gemm_qkv<<<dim3(18, 16), 256, 0, stream>>>(x, W_attn, b_attn, qh, kh, vh);

    // dpp: one wave per (head, token): grid (24, 512/4)
    dpp_kernel<<<dim3(BH, Tn / 4), 256, 0, stream>>>(qh, kh, vh, yf);

    // output projection: grid (768/128, 1024/64) = (6, 16)
    gemm_proj<<<dim3(6, 16), 256, 0, stream>>>(yf, W_proj, b_proj, out);
}

// Round 3
// 221.903 us; speedup vs baseline: 2.4848x; 1.5690x over previous
//
#include <hip/hip_runtime.h>
#include <math.h>

#define Bn 2
#define Hn 12
#define Tn 512
#define Cn 768
#define HS 64
#define BH 24
#define MTOP 8
#define NCOMB 36
#define NEGV -1e30f

// combo tables: slots (0..7) for size-1 (8 combos) then size-2 (28 combos), lexicographic
__device__ __constant__ int C_SL0[NCOMB] = {
  0,1,2,3,4,5,6,7,
  0,0,0,0,0,0,0,
  1,1,1,1,1,1,
  2,2,2,2,2,
  3,3,3,3,
  4,4,4,
  5,5,
  6};
__device__ __constant__ int C_SL1[NCOMB] = {
  -1,-1,-1,-1,-1,-1,-1,-1,
  1,2,3,4,5,6,7,
  2,3,4,5,6,7,
  3,4,5,6,7,
  4,5,6,7,
  5,6,7,
  6,7,
  7};

// gram pair tables: 45 pairs (a<=b) over 9 tokens
__device__ __constant__ int PA[45] = {
  0,0,0,0,0,0,0,0,0,
  1,1,1,1,1,1,1,1,
  2,2,2,2,2,2,2,
  3,3,3,3,3,3,
  4,4,4,4,4,
  5,5,5,5,
  6,6,6,
  7,7,
  8};
__device__ __constant__ int PB[45] = {
  0,1,2,3,4,5,6,7,8,
  1,2,3,4,5,6,7,8,
  2,3,4,5,6,7,8,
  3,4,5,6,7,8,
  4,5,6,7,8,
  5,6,7,8,
  6,7,8,
  7,8,
  8};

// ---------------- generic 64x64-tile fp32 GEMM: out = A @ W^T + bias ------------------
// SCATTER=true: qkv epilogue scattering to per-head q/k/v; false: plain row-major store.
// BK=16, register-prefetch double buffer, micro 4x4 (conflict-light float4 LDS reads).
template<bool SCATTER>
__global__ __launch_bounds__(256) void gemm64(const float* __restrict__ A,
                                              const float* __restrict__ W,
                                              const float* __restrict__ bias,
                                              float* __restrict__ out,
                                              float* __restrict__ qh,
                                              float* __restrict__ kh,
                                              float* __restrict__ vh) {
    __shared__ float As[16][68];   // As[kk][m]
    __shared__ float Bs[16][68];   // Bs[kk][n]
    const int tn = blockIdx.x * 64;
    const int tm = blockIdx.y * 64;
    const int tid = threadIdx.x;
    const int tx = tid & 15;       // n dir
    const int ty = tid >> 4;       // m dir
    const int lm  = tid >> 2;      // staging row (0..63)
    const int lkc = (tid & 3) * 4; // staging k offset (0,4,8,12)

    const float* pA = A + (size_t)(tm + lm) * Cn + lkc;
    const float* pB = W + (size_t)(tn + lm) * Cn + lkc;
    float4 ra = *(const float4*)pA;
    float4 rb = *(const float4*)pB;

    float acc[4][4] = {};
    for (int k0 = 0; k0 < Cn; k0 += 16) {
        As[lkc+0][lm] = ra.x; As[lkc+1][lm] = ra.y; As[lkc+2][lm] = ra.z; As[lkc+3][lm] = ra.w;
        Bs[lkc+0][lm] = rb.x; Bs[lkc+1][lm] = rb.y; Bs[lkc+2][lm] = rb.z; Bs[lkc+3][lm] = rb.w;
        __syncthreads();
        if (k0 + 16 < Cn) {        // prefetch next K-slab; overlaps the 16 k-steps below
            ra = *(const float4*)(pA + k0 + 16);
            rb = *(const float4*)(pB + k0 + 16);
        }
        #pragma unroll
        for (int kk = 0; kk < 16; ++kk) {
            float4 a4 = *(const float4*)&As[kk][ty * 4];
            float4 b4 = *(const float4*)&Bs[kk][tx * 4];
            float am[4] = {a4.x, a4.y, a4.z, a4.w};
            float bn[4] = {b4.x, b4.y, b4.z, b4.w};
            #pragma unroll
            for (int um = 0; um < 4; ++um)
                #pragma unroll
                for (int un = 0; un < 4; ++un)
                    acc[um][un] += am[um] * bn[un];
        }
        __syncthreads();
    }

    float bv[4];
    #pragma unroll
    for (int un = 0; un < 4; ++un) bv[un] = bias[tn + tx * 4 + un];

    if (!SCATTER) {
        #pragma unroll
        for (int um = 0; um < 4; ++um) {
            int m = tm + ty * 4 + um;
            float4 o = {acc[um][0] + bv[0], acc[um][1] + bv[1],
                        acc[um][2] + bv[2], acc[um][3] + bv[3]};
            *(float4*)(out + (size_t)m * Cn + tn + tx * 4) = o;
        }
    } else {
        // 64-col tile lies entirely within one qkv part and one head
        const int part = tn / Cn;
        const int c0 = tn - part * Cn;
        const int h = c0 >> 6;
        const int d = tx * 4;
        float* dst = (part == 0) ? qh : ((part == 1) ? kh : vh);
        #pragma unroll
        for (int um = 0; um < 4; ++um) {
            int m = tm + ty * 4 + um;
            int bb = m >> 9, t = m & 511;
            float4 o = {acc[um][0] + bv[0], acc[um][1] + bv[1],
                        acc[um][2] + bv[2], acc[um][3] + bv[3]};
            *(float4*)(dst + ((size_t)((bb * Hn) + h) * Tn + t) * HS + d) = o;
        }
    }
}

// ---------------- DPP selection: one WAVE per token, 4 consecutive tokens/block -------
// K-prefix scanned via shared LDS chunks (4-way reuse across the block's waves).
__global__ __launch_bounds__(256, 4) void dpp_kernel(const float* __restrict__ qh,
                                                     const float* __restrict__ kh,
                                                     const float* __restrict__ vh,
                                                     float* __restrict__ yflat) {
    const int bh = blockIdx.x;
    const int i0 = blockIdx.y * 4;
    const int w = threadIdx.x >> 6;
    const int lane = threadIdx.x & 63;
    const int i = i0 + w;

    __shared__ float Klds[64][68];     // K-chunk staging (17.4 KB), stride 17 f4-groups
    __shared__ float Ksh[4][9][68];    // selected K rows (b128 gram reads)
    __shared__ float Vsh[4][9][65];    // selected V rows (b32 lane-stride reads)
    __shared__ float Gsh[4][81];
    __shared__ float qdsh[4][12];
    __shared__ float PW[4][36][4];

    const float* qp    = qh + (size_t)(bh * Tn + i) * HS;
    const float* kbase = kh + (size_t)bh * Tn * HS;
    const float* vbase = vh + (size_t)bh * Tn * HS;

    // q_i resident in registers for the whole sim phase
    float4 qv[16];
    #pragma unroll
    for (int t = 0; t < 16; ++t) qv[t] = ((const float4*)qp)[t];

    float sv[8];
    #pragma unroll
    for (int r = 0; r < 8; ++r) sv[r] = -INFINITY;

    const int cmax = (i0 + 3) >> 6;    // block-uniform
    const int rmax = i >> 6;

    #pragma unroll
    for (int c = 0; c < 8; ++c) {
        if (c <= cmax) {
            // cooperative stage: 64 rows x 64 floats = 1024 float4, 4/thread, coalesced
            const float4* src = (const float4*)(kbase + (size_t)c * 64 * HS);
            #pragma unroll
            for (int u = 0; u < 4; ++u) {
                int e = threadIdx.x + u * 256;
                int r = e >> 4, t = e & 15;
                *(float4*)&Klds[r][t * 4] = src[e];
            }
            __syncthreads();
            if (c <= rmax) {
                const int j = c * 64 + lane;
                const float4* kr = (const float4*)&Klds[lane][0];
                float acc = 0.f;
                #pragma unroll
                for (int t = 0; t < 16; ++t) {
                    float4 kv = kr[t];
                    acc += kv.x * qv[t].x; acc += kv.y * qv[t].y;
                    acc += kv.z * qv[t].z; acc += kv.w * qv[t].w;
                }
                sv[c] = (j <= i) ? acc : -INFINITY;
            }
            __syncthreads();
        }
    }

    // qd0 = sim[i] = k_i . q_i (unmasked since j==i passes causal test)
    float qd0 = 0.f;
    #pragma unroll
    for (int c = 0; c < 8; ++c) {
        float t = __shfl(sv[c], i & 63, 64);
        if (c == rmax) qd0 = t;
    }

    // top-8: 8 in-register butterfly argmax passes (value desc, tie -> lower index)
    float topv[8]; int topi[8];
    #pragma unroll
    for (int p = 0; p < MTOP; ++p) {
        float bv = -INFINITY; int bi = 0x7fffffff;
        #pragma unroll
        for (int r = 0; r < 8; ++r) {
            int j = r * 64 + lane;
            float v = sv[r];
            if (v > bv || (v == bv && j < bi)) { bv = v; bi = j; }
        }
        #pragma unroll
        for (int off = 32; off > 0; off >>= 1) {
            float ov = __shfl_xor(bv, off, 64);
            int   oi = __shfl_xor(bi, off, 64);
            if (ov > bv || (ov == bv && oi < bi)) { bv = ov; bi = oi; }
        }
        topv[p] = bv; topi[p] = bi;
        const int rs = bi >> 6, ls = bi & 63;
        #pragma unroll
        for (int r = 0; r < 8; ++r)
            if (r == rs && lane == ls) sv[r] = -INFINITY;
    }

    // validity bitmask per slot (wave-uniform)
    const int n_cand = (i + 1 < MTOP) ? (i + 1) : MTOP;
    int vmask = 0;
    #pragma unroll
    for (int s = 0; s < MTOP; ++s)
        if (s < n_cand && topi[s] != i) vmask |= (1 << s);

    // stage selected K/V rows {i} U top_idx (coalesced, lane = d)
    #pragma unroll
    for (int a = 0; a < 9; ++a) {
        int t = (a == 0) ? i : topi[a - 1];
        Ksh[w][a][lane] = kbase[(size_t)t * HS + lane];
        Vsh[w][a][lane] = vbase[(size_t)t * HS + lane];
    }
    if (lane < 9) {
        float val = qd0;
        #pragma unroll
        for (int p = 0; p < 8; ++p) if (lane == p + 1) val = topv[p];
        qdsh[w][lane] = val;
    }
    __syncthreads();

    // gram: lane l < 45 computes pair (PA[l], PB[l])
    if (lane < 45) {
        const int a = PA[lane], b = PB[lane];
        const float4* rka = (const float4*)&Ksh[w][a][0];
        const float4* rkb = (const float4*)&Ksh[w][b][0];
        float acc = 0.f;
        #pragma unroll
        for (int t = 0; t < 16; ++t) {
            float4 fa = rka[t], fb = rkb[t];
            acc += fa.x * fb.x; acc += fa.y * fb.y;
            acc += fa.z * fb.z; acc += fa.w * fb.w;
        }
        Gsh[w][a * 9 + b] = acc;
        Gsh[w][b * 9 + a] = acc;
    }
    __syncthreads();

    // combos on lanes 0..35
    float score = -INFINITY;
    int ca = 0, cb = 0, sdim = 1;
    if (lane < NCOMB) {
        const int sl0 = C_SL0[lane], sl1 = C_SL1[lane];
        sdim = (sl1 < 0) ? 1 : 2;
        ca = sl0 + 1;
        cb = (sl1 < 0) ? 0 : sl1 + 1;
        bool valid = ((vmask >> sl0) & 1);
        if (sdim == 2) valid = valid && ((vmask >> sl1) & 1);
        float G00 = Gsh[w][0];
        float Gaa = Gsh[w][ca * 9 + ca];
        float G0a = Gsh[w][ca];
        float det;
        if (sdim == 1) {
            det = G00 * Gaa - G0a * G0a;
        } else {
            float G0b = Gsh[w][cb];
            float Gab = Gsh[w][ca * 9 + cb];
            float Gbb = Gsh[w][cb * 9 + cb];
            det = G00 * (Gaa * Gbb - Gab * Gab)
                - G0a * (G0a * Gbb - Gab * G0b)
                + G0b * (G0a * Gab - Gaa * G0b);
        }
        score = valid ? (logf(det + 1e-6f) / (float)(sdim + 1)) : NEGV;
    }
    // softmax over scores via butterfly (lanes>=36 contribute -inf / 0)
    float mx = score;
    #pragma unroll
    for (int off = 32; off > 0; off >>= 1) mx = fmaxf(mx, __shfl_xor(mx, off, 64));
    float e = (lane < NCOMB) ? expf(score - mx) : 0.f;
    float sum = e;
    #pragma unroll
    for (int off = 32; off > 0; off >>= 1) sum += __shfl_xor(sum, off, 64);
    const bool hasValid = (mx > -1e29f);

    if (lane < NCOMB) {
        float prob = e / sum;
        float d0 = qdsh[w][0]  * 0.125f;
        float d1 = qdsh[w][ca] * 0.125f;
        float d2 = (sdim == 2) ? qdsh[w][cb] * 0.125f : -INFINITY;
        float m2 = fmaxf(fmaxf(d0, d1), d2);
        float e0 = expf(d0 - m2), e1 = expf(d1 - m2);
        float e2 = (sdim == 2) ? expf(d2 - m2) : 0.f;
        float inv = prob / (e0 + e1 + e2);
        float4 pw = {e0 * inv, e1 * inv, e2 * inv, 0.f};
        *(float4*)&PW[w][lane][0] = pw;
    }
    __syncthreads();

    // y[d], d = lane
    const float v0 = Vsh[w][0][lane];
    float y;
    if (!hasValid) {
        y = v0;
    } else {
        float acc = 0.f;
        #pragma unroll
        for (int c = 0; c < NCOMB; ++c) {
            float4 pw = *(const float4*)&PW[w][c][0];
            int a = C_SL0[c] + 1;
            int b = (C_SL1[c] < 0) ? 0 : C_SL1[c] + 1;   // pw.z == 0 when sdim==1
            acc += pw.x * v0 + pw.y * Vsh[w][a][lane] + pw.z * Vsh[w][b][lane];
        }
        y = acc;
    }
    const int bb = bh / Hn, h = bh % Hn;
    yflat[((size_t)(bb * Tn + i)) * Cn + h * HS + lane] = y;
}

extern "C" void kernel_launch(void* const* d_in, const int* in_sizes, int n_in,
                              void* d_out, int out_size, void* d_ws, size_t ws_size,
                              hipStream_t stream) {
    const float* x      = (const float*)d_in[0];
    const float* W_attn = (const float*)d_in[1];
    const float* b_attn = (const float*)d_in[2];
    const float* W_proj = (const float*)d_in[3];
    const float* b_proj = (const float*)d_in[4];
    float* out = (float*)d_out;

    float* ws = (float*)d_ws;
    const size_t per = (size_t)BH * Tn * HS;  // 786432 floats
    float* qh = ws;
    float* kh = ws + per;
    float* vh = ws + 2 * per;
    float* yf = ws + 3 * per;

    // qkv projection: 64x64 tiles -> grid (2304/64, 1024/64) = (36, 16) = 576 blocks
    gemm64<true><<<dim3(36, 16), 256, 0, stream>>>(x, W_attn, b_attn, nullptr, qh, kh, vh);

    // dpp: one wave per (head, token), 4 consecutive tokens per block
    dpp_kernel<<<dim3(BH, Tn / 4), 256, 0, stream>>>(qh, kh, vh, yf);

    // output projection: grid (768/64, 1024/64) = (12, 16) = 192 blocks
    gemm64<false><<<dim3(12, 16), 256, 0, stream>>>(yf, W_proj, b_proj, out, nullptr, nullptr, nullptr);
}